// Round 13
// baseline (1858.704 us; speedup 1.0000x reference)
//
#include <hip/hip_runtime.h>

#define N_USERS 1000000
#define NEDGE   32000000
#define OUT_F   64
#define BN_EPS  1e-5f

// Destination binning geometry (1D).
// S_BUCKET=4096 is the max where meta packs: dst_local(12b)<<20 | src(20b).
#define SBITS     12
#define S_BUCKET  4096
#define NB        245                     // ceil(N_USERS / S_BUCKET)
#define CAP       136896                  // mean 130612 + ~17 sigma, mult of 16
#define SCAT_BLOCKS 1024
#define TILE      4096                    // edges per scatter tile (LDS-sorted)
#define NTILES    ((NEDGE + TILE - 1) / TILE)
#define SPLIT     16                      // blocks per bucket in the hop (occupancy)

typedef unsigned int uint4v __attribute__((ext_vector_type(4)));
typedef int          int4v  __attribute__((ext_vector_type(4)));
typedef float        flt4v  __attribute__((ext_vector_type(4)));

// ---------------- binned path ----------------

__global__ void init_cursors(unsigned* __restrict__ cursors) {
    int i = blockIdx.x * blockDim.x + threadIdx.x;
    if (i < NB) cursors[i] = (unsigned)i * CAP;
}

// Tile-sorted scatter: counting-sort a 4096-edge tile by dst bucket in LDS,
// reserve one contiguous global range per (tile,bucket), flush coalesced runs.
// Vector nt loads issued up-front (round-12: 512->233us from this MLP).
__global__ __launch_bounds__(256) void scatter_bin(
    const int* __restrict__ src, const int* __restrict__ dst,
    const float* __restrict__ ew, uint2* __restrict__ rec,
    unsigned* __restrict__ cursors) {
    __shared__ uint2 srec[TILE];             // 32KB tile records, bucket-sorted
    __shared__ unsigned short sbkt[TILE];    // 8KB bucket id per sorted pos
    __shared__ unsigned hist[NB];
    __shared__ unsigned curs[NB];
    __shared__ unsigned gpos[NB];
    __shared__ unsigned chunkT[256];
    int tid = threadIdx.x;

    for (int tile = blockIdx.x; tile < NTILES; tile += gridDim.x) {
        int e0 = tile * TILE;
        int n_this = (e0 + TILE <= NEDGE) ? TILE : (NEDGE - e0);  // mult of 4
        int nq = n_this >> 2;                                     // int4 count
        int q0 = e0 >> 2;

        for (int i = tid; i < NB; i += 256) hist[i] = 0;
        __syncthreads();

        int4v dv[4]; int4v sv[4]; flt4v wv[4];
        #pragma unroll
        for (int k = 0; k < 4; ++k) {
            int q = k * 256 + tid;
            if (q < nq) {
                dv[k] = __builtin_nontemporal_load(reinterpret_cast<const int4v*>(dst) + q0 + q);
                sv[k] = __builtin_nontemporal_load(reinterpret_cast<const int4v*>(src) + q0 + q);
                wv[k] = __builtin_nontemporal_load(reinterpret_cast<const flt4v*>(ew) + q0 + q);
            }
        }
        #pragma unroll
        for (int k = 0; k < 4; ++k) {
            int q = k * 256 + tid;
            if (q < nq) {
                #pragma unroll
                for (int j = 0; j < 4; ++j)
                    atomicAdd(&hist[dv[k][j] >> SBITS], 1u);
            }
        }
        __syncthreads();

        // parallel exclusive scan over hist[NB] (proven round-10/11 pattern)
        {
            int base = tid * 4;
            unsigned run = 0;
            #pragma unroll
            for (int k = 0; k < 4; ++k) {
                int idx = base + k;
                unsigned v = (idx < NB) ? hist[idx] : 0u;
                if (idx < NB) hist[idx] = run;
                run += v;
            }
            chunkT[tid] = run;
        }
        __syncthreads();
        if (tid == 0) {
            unsigned r = 0;
            for (int t = 0; t < 256; ++t) { unsigned v = chunkT[t]; chunkT[t] = r; r += v; }
        }
        __syncthreads();
        {
            int base = tid * 4;
            unsigned add = chunkT[tid];
            #pragma unroll
            for (int k = 0; k < 4; ++k) {
                int idx = base + k;
                if (idx < NB) hist[idx] += add;
            }
        }
        __syncthreads();

        for (int b = tid; b < NB; b += 256) {
            unsigned st = hist[b];
            unsigned en = (b == NB - 1) ? (unsigned)n_this : hist[b + 1];
            unsigned c = en - st;
            gpos[b] = c ? atomicAdd(&cursors[b], c) : 0u;
            curs[b] = 0;
        }
        __syncthreads();

        #pragma unroll
        for (int k = 0; k < 4; ++k) {
            int q = k * 256 + tid;
            if (q < nq) {
                #pragma unroll
                for (int j = 0; j < 4; ++j) {
                    int dd = dv[k][j], ss = sv[k][j];
                    int b = dd >> SBITS;
                    unsigned p = hist[b] + atomicAdd(&curs[b], 1u);
                    srec[p] = make_uint2(((unsigned)(dd & (S_BUCKET - 1)) << 20) | (unsigned)ss,
                                         __float_as_uint(wv[k][j]));
                    sbkt[p] = (unsigned short)b;
                }
            }
        }
        __syncthreads();

        for (int i = tid; i < n_this; i += 256) {   // coalesced segment flush
            unsigned b = sbkt[i];
            rec[gpos[b] + ((unsigned)i - hist[b])] = srec[i];
        }
        __syncthreads();                            // before next tile reuses LDS
    }
}

// LDS-accumulation hop: SPLIT blocks per 4096-node bucket; stream records (nt),
// gather cur[src], ds_add_f32 into 16KB accumulator, coalesced global atomicAdd
// flush (nxt pre-zeroed). 16 records/iter (8x uint4 nt loads) keep 16
// independent gathers in flight per lane; round-12 showed depth 4->8 cut hop
// 310->232us (latency/MLP-bound), so push depth + occupancy (SPLIT 8->16).
__global__ __launch_bounds__(256) void hop_bucket(
    const uint2* __restrict__ rec, const unsigned* __restrict__ cursors,
    const float* __restrict__ cur, float* __restrict__ nxt) {
    __shared__ float acc[S_BUCKET];
    int tid = threadIdx.x;
    int b = blockIdx.x / SPLIT;
    int sidx = blockIdx.x % SPLIT;
    for (int i = tid; i < S_BUCKET; i += 256) acc[i] = 0.0f;
    __syncthreads();

    unsigned start = (unsigned)b * CAP;          // CAP mult of 16 -> 128B aligned
    unsigned cnt = cursors[b] - start;
    unsigned u0 = ((cnt * (unsigned)sidx) / SPLIT) & ~15u;
    unsigned u1 = (sidx == SPLIT - 1) ? cnt : (((cnt * (unsigned)(sidx + 1)) / SPLIT) & ~15u);
    const uint2* bp = rec + start;

    unsigned i = u0 + 16u * (unsigned)tid;
    for (; i + 16u <= u1; i += 16u * 256u) {
        uint4v r[8];
        #pragma unroll
        for (int k = 0; k < 8; ++k)
            r[k] = __builtin_nontemporal_load(reinterpret_cast<const uint4v*>(bp + i + 2 * k));
        float c[16];
        #pragma unroll
        for (int k = 0; k < 8; ++k) {
            c[2 * k]     = cur[r[k].x & 0xFFFFFu];
            c[2 * k + 1] = cur[r[k].z & 0xFFFFFu];
        }
        #pragma unroll
        for (int k = 0; k < 8; ++k) {
            atomicAdd(&acc[r[k].x >> 20], c[2 * k]     * __uint_as_float(r[k].y));
            atomicAdd(&acc[r[k].z >> 20], c[2 * k + 1] * __uint_as_float(r[k].w));
        }
    }
    if (i < u1) {                                // straddling remainder (<16), one thread
        for (unsigned j = i; j < i + 16u && j < u1; ++j) {
            uint2 rr = bp[j];
            atomicAdd(&acc[rr.x >> 20], cur[rr.x & 0xFFFFFu] * __uint_as_float(rr.y));
        }
    }
    __syncthreads();

    int nb0 = b << SBITS;
    for (int k = tid; k < S_BUCKET; k += 256) {
        int n = nb0 + k;
        if (n < N_USERS) atomicAdd(&nxt[n], acc[k]);
    }
}

// ---------------- fallback path (device atomics, small workspace) ----------------

__global__ void zero_kernel(float* __restrict__ p, int n) {
    int i = blockIdx.x * blockDim.x + threadIdx.x;
    int stride = gridDim.x * blockDim.x;
    for (; i < n; i += stride) p[i] = 0.0f;
}

__global__ __launch_bounds__(256) void hop_atomic(
    const int* __restrict__ src, const int* __restrict__ dst,
    const float* __restrict__ ew, const float* __restrict__ cur,
    float* __restrict__ nxt) {
    int e = blockIdx.x * blockDim.x + threadIdx.x;
    if (e * 4 < NEDGE) {
        int4   s = ((const int4*)src)[e];
        int4   d = ((const int4*)dst)[e];
        float4 w = ((const float4*)ew)[e];
        atomicAdd(&nxt[d.x], cur[s.x] * w.x);
        atomicAdd(&nxt[d.y], cur[s.y] * w.y);
        atomicAdd(&nxt[d.z], cur[s.z] * w.z);
        atomicAdd(&nxt[d.w], cur[s.w] * w.w);
    }
}

// ---------------- finalize: 5->64 matvec + BatchNorm over features ----------------

__global__ __launch_bounds__(256) void finalize_kernel(
    const float* __restrict__ x,  const float* __restrict__ f1,
    const float* __restrict__ f2, const float* __restrict__ f3,
    const float* __restrict__ f4, const float* __restrict__ W,
    const float* __restrict__ bias, const float* __restrict__ gamma,
    const float* __restrict__ beta, float* __restrict__ out) {
    int lane = threadIdx.x & 63;
    int waveInBlock = threadIdx.x >> 6;
    int wavesPerBlock = blockDim.x >> 6;
    int gwave  = blockIdx.x * wavesPerBlock + waveInBlock;
    int nwaves = gridDim.x * wavesPerBlock;

    float w0 = W[lane * 5 + 0];
    float w1 = W[lane * 5 + 1];
    float w2 = W[lane * 5 + 2];
    float w3 = W[lane * 5 + 3];
    float w4 = W[lane * 5 + 4];
    float b  = bias[lane];

    for (int n = gwave; n < N_USERS; n += nwaves) {
        float c0 = x[n], c1 = f1[n], c2 = f2[n], c3 = f3[n], c4 = f4[n];
        float y = b + c0 * w0 + c1 * w1 + c2 * w2 + c3 * w3 + c4 * w4;

        float s = y;
        #pragma unroll
        for (int off = 32; off; off >>= 1) s += __shfl_xor(s, off);
        float mean = s * (1.0f / 64.0f);

        float d = y - mean;
        float v = d * d;
        #pragma unroll
        for (int off = 32; off; off >>= 1) v += __shfl_xor(v, off);
        float var = v * (1.0f / 64.0f);

        float o = d * rsqrtf(var + BN_EPS) * gamma[n] + beta[n];
        __builtin_nontemporal_store(o, &out[(size_t)n * OUT_F + lane]);
    }
}

extern "C" void kernel_launch(void* const* d_in, const int* in_sizes, int n_in,
                              void* d_out, int out_size, void* d_ws, size_t ws_size,
                              hipStream_t stream) {
    const float* x     = (const float*)d_in[0];
    const int*   ei    = (const int*)d_in[1];
    const float* ew    = (const float*)d_in[2];
    const float* W     = (const float*)d_in[3];
    const float* bias  = (const float*)d_in[4];
    const float* gamma = (const float*)d_in[5];
    const float* beta  = (const float*)d_in[6];
    float* out = (float*)d_out;

    const int* src = ei;
    const int* dst = ei + NEDGE;

    // Workspace layout (total ~284.3MB; known-available >= 304MB from rounds 0-1)
    float* f = (float*)d_ws;                                   // 16MB
    uint2* rec = (uint2*)(f + 4ull * N_USERS);                 // 268.3MB (padded)
    unsigned* cursors = (unsigned*)(rec + (size_t)NB * CAP);   // 4KB
    size_t needed = 16000000ull + (size_t)NB * CAP * 8 + 4096;

    if (ws_size >= needed) {
        init_cursors<<<1, 256, 0, stream>>>(cursors);
        zero_kernel<<<2048, 256, 0, stream>>>(f, 4 * N_USERS);   // hop flush is atomicAdd
        scatter_bin<<<SCAT_BLOCKS, 256, 0, stream>>>(src, dst, ew, rec, cursors);
        const float* cur = x;
        for (int h = 0; h < 4; ++h) {
            float* nxt = f + (size_t)h * N_USERS;
            hop_bucket<<<NB * SPLIT, 256, 0, stream>>>(rec, cursors, cur, nxt);
            cur = nxt;
        }
    } else {
        zero_kernel<<<4096, 256, 0, stream>>>(f, 4 * N_USERS);
        const float* cur = x;
        for (int h = 0; h < 4; ++h) {
            float* nxt = f + (size_t)h * N_USERS;
            hop_atomic<<<NEDGE / 4 / 256, 256, 0, stream>>>(src, dst, ew, cur, nxt);
            cur = nxt;
        }
    }

    finalize_kernel<<<2048, 256, 0, stream>>>(
        x, f, f + N_USERS, f + 2 * N_USERS, f + 3 * N_USERS,
        W, bias, gamma, beta, out);
}